// Round 1
// baseline (339.215 us; speedup 1.0000x reference)
//
#include <hip/hip_runtime.h>
#include <hip/hip_bf16.h>

// FlaxLinear irrep-wise linear: 9 channel-GEMMs (M=4096, K=512, N=512).
// Channel c: block 0 (d=1,i=0), block 1 (d=3,i=0..2), block 2 (d=5,i=0..4).
// x element for channel: x[b, xoff + u*d + i]; out[b, xoff + w*d + i].
// bf16 MFMA (16x16x32), fp32 accumulate; threshold is bf16-grade (0.11).

#define BM 128
#define BN 128
#define BK 32
#define LDA 40  // padded row stride (bf16 elems) for As
#define LDB 40  // padded row stride for Bs
#define DTOT 4608
#define NMUL 512

typedef __attribute__((ext_vector_type(8))) short short8;
typedef __attribute__((ext_vector_type(4))) float float4v;

__device__ __forceinline__ unsigned short f2bf(float f) {
    // round-to-nearest-even f32 -> bf16
    unsigned int u = __builtin_bit_cast(unsigned int, f);
    unsigned int r = 0x7fffu + ((u >> 16) & 1u);
    return (unsigned short)((u + r) >> 16);
}

__global__ __launch_bounds__(256) void flax_linear_kernel(
    const float* __restrict__ x,
    const float* __restrict__ w0,
    const float* __restrict__ w1,
    const float* __restrict__ w2,
    const float* __restrict__ b0,
    float* __restrict__ out)
{
    const float PW = 0.044194173824159216f;  // 512^-0.5

    const int c = blockIdx.z;
    const float* W;
    int xoff, d, irr;
    if (c == 0)      { W = w0; xoff = 0;    d = 1; irr = 0; }
    else if (c < 4)  { W = w1; xoff = 512;  d = 3; irr = c - 1; }
    else             { W = w2; xoff = 2048; d = 5; irr = c - 4; }

    const int n0 = blockIdx.x * BN;
    const int m0 = blockIdx.y * BM;

    __shared__ __align__(16) unsigned short As[BM * LDA];  // As[m][k]
    __shared__ __align__(16) unsigned short Bs[BN * LDB];  // Bs[n][k] = W[k][n] (transposed tile)

    const int tid = threadIdx.x;
    const int lane = tid & 63;
    const int wv = tid >> 6;          // wave 0..3
    const int wm = (wv >> 1) * 64;    // wave's m-quadrant
    const int wn = (wv & 1) * 64;     // wave's n-quadrant
    const int lr = lane & 15;         // row (A) / col (B,C)
    const int lq = lane >> 4;         // quad

    // staging maps
    const int arow = tid >> 3;        // 0..31 (row within 32-row pass)
    const int ak   = (tid & 7) * 4;   // k base 0..28
    const int bk   = tid >> 5;        // 0..7 (k within 8-row pass)
    const int bn   = (tid & 31) * 4;  // n base 0..124

    float4v acc[4][4];
#pragma unroll
    for (int a = 0; a < 4; ++a)
#pragma unroll
        for (int b = 0; b < 4; ++b) acc[a][b] = (float4v)0.f;

    for (int kt = 0; kt < NMUL / BK; ++kt) {
        // ---- stage A tile: rows m0..m0+127, k = kt*32..+31 (global stride d) ----
#pragma unroll
        for (int p = 0; p < 4; ++p) {
            const int r = p * 32 + arow;
            const float* src = x + (size_t)(m0 + r) * DTOT + xoff + (kt * BK + ak) * d + irr;
            float vals[4];
            if (d == 1) {
                float4v v = *(const float4v*)src;
#pragma unroll
                for (int j = 0; j < 4; ++j) vals[j] = v[j];
            } else {
#pragma unroll
                for (int j = 0; j < 4; ++j) vals[j] = src[j * d];
            }
#pragma unroll
            for (int j = 0; j < 4; ++j) As[r * LDA + ak + j] = f2bf(vals[j]);
        }
        // ---- stage B tile: W[k][n] -> Bs[n][k], coalesced read along n ----
#pragma unroll
        for (int p = 0; p < 4; ++p) {
            const int k = p * 8 + bk;
            const float* src = W + (size_t)(kt * BK + k) * NMUL + n0 + bn;
            float4v v = *(const float4v*)src;
#pragma unroll
            for (int j = 0; j < 4; ++j) Bs[(bn + j) * LDB + k] = f2bf(v[j]);
        }
        __syncthreads();

        // ---- MFMA: each wave does 4x4 tiles of 16x16 over its 64x64 quadrant ----
        short8 afr[4], bfr[4];
#pragma unroll
        for (int mi = 0; mi < 4; ++mi)
            afr[mi] = *(const short8*)&As[(wm + mi * 16 + lr) * LDA + lq * 8];
#pragma unroll
        for (int ni = 0; ni < 4; ++ni)
            bfr[ni] = *(const short8*)&Bs[(wn + ni * 16 + lr) * LDB + lq * 8];
#pragma unroll
        for (int mi = 0; mi < 4; ++mi)
#pragma unroll
            for (int ni = 0; ni < 4; ++ni)
                acc[mi][ni] = __builtin_amdgcn_mfma_f32_16x16x32_bf16(
                    afr[mi], bfr[ni], acc[mi][ni], 0, 0, 0);
        __syncthreads();
    }

    // ---- epilogue: C row=(lane>>4)*4+reg, col=lane&15 ----
#pragma unroll
    for (int mi = 0; mi < 4; ++mi) {
#pragma unroll
        for (int ni = 0; ni < 4; ++ni) {
            const int wcol = n0 + wn + ni * 16 + lr;
            float bias = (c == 0) ? b0[wcol] : 0.f;
#pragma unroll
            for (int r = 0; r < 4; ++r) {
                const int row = m0 + wm + mi * 16 + lq * 4 + r;
                out[(size_t)row * DTOT + xoff + wcol * d + irr] =
                    acc[mi][ni][r] * PW + bias;
            }
        }
    }
}

extern "C" void kernel_launch(void* const* d_in, const int* in_sizes, int n_in,
                              void* d_out, int out_size, void* d_ws, size_t ws_size,
                              hipStream_t stream) {
    const float* x  = (const float*)d_in[0];
    const float* w0 = (const float*)d_in[1];
    const float* w1 = (const float*)d_in[2];
    const float* w2 = (const float*)d_in[3];
    const float* b0 = (const float*)d_in[4];
    float* out = (float*)d_out;

    dim3 grid(NMUL / BN, 4096 / BM, 9);  // 4 x 32 x 9 = 1152 blocks
    dim3 block(256);
    flax_linear_kernel<<<grid, block, 0, stream>>>(x, w0, w1, w2, b0, out);
}